// Round 1
// baseline (308.478 us; speedup 1.0000x reference)
//
#include <hip/hip_runtime.h>
#include <hip/hip_bf16.h>
#include <stdint.h>

#define NQ 2048
#define NKV 2048
#define DIM 1024
#define INNER 1024
#define HEADS 16
#define DH 64
#define BATCH 2

typedef float f32x4 __attribute__((ext_vector_type(4)));
typedef __bf16 bf16x8 __attribute__((ext_vector_type(8)));
typedef unsigned int u32x4 __attribute__((ext_vector_type(4)));

__device__ inline ushort f2b(float f) {
    uint32_t u = __builtin_bit_cast(uint32_t, f);
    u += 0x7fff + ((u >> 16) & 1);   // round-to-nearest-even
    return (ushort)(u >> 16);
}

// ---------------- fp32 -> bf16 convert (vectorized) ----------------
__global__ void cvt_f32_bf16(const float* __restrict__ in, ushort* __restrict__ out, int n4) {
    int i = blockIdx.x * blockDim.x + threadIdx.x;
    int stride = gridDim.x * blockDim.x;
    for (; i < n4; i += stride) {
        float4 v = ((const float4*)in)[i];
        ushort4 o;
        o.x = f2b(v.x); o.y = f2b(v.y); o.z = f2b(v.z); o.w = f2b(v.w);
        ((ushort4*)out)[i] = o;
    }
}

// ---------------- transpose + convert: in[R][C] f32 -> out[C][R] bf16 ----------------
__global__ void transp_cvt(const float* __restrict__ in, ushort* __restrict__ out, int R, int C) {
    __shared__ ushort tile[32][33];
    int c0 = blockIdx.x * 32, r0 = blockIdx.y * 32;
    int tx = threadIdx.x, ty = threadIdx.y;   // 32 x 8
#pragma unroll
    for (int i = 0; i < 4; i++)
        tile[ty + i * 8][tx] = f2b(in[(size_t)(r0 + ty + i * 8) * C + c0 + tx]);
    __syncthreads();
#pragma unroll
    for (int i = 0; i < 4; i++)
        out[(size_t)(c0 + ty + i * 8) * R + r0 + tx] = tile[tx][ty + i * 8];
}

// ---------------- bf16 GEMM: C[M][N] = A[M][K] * Bt[N][K]^T ----------------
// MODE 0: bf16 out -> C0[M][N]
// MODE 1: bf16 split -> C0[M][0:1024], C1[M][1024:2048]
// MODE 2: f32 out + bias -> C0[M][N]
template <int MODE>
__global__ __launch_bounds__(256) void gemm_bt(const ushort* __restrict__ A, const ushort* __restrict__ Bt,
                                               void* __restrict__ C0, void* __restrict__ C1,
                                               const float* __restrict__ bias,
                                               int M, int N, int K) {
    __shared__ ushort As[4 * 128 * 8];   // [kc][row][8]
    __shared__ ushort Bs[4 * 128 * 8];
    int m0 = blockIdx.y * 128, n0 = blockIdx.x * 128;
    int t = threadIdx.x, l = t & 63, w = t >> 6;
    int wr = w >> 1, wc = w & 1;
    int lg = l >> 4, lc = l & 15;
    f32x4 acc[4][4] = {};
    for (int k0 = 0; k0 < K; k0 += 32) {
        __syncthreads();
        {
            int kc = t >> 6;          // 0..3
            int rr = t & 63;
#pragma unroll
            for (int p = 0; p < 2; p++) {
                int row = p * 64 + rr;
                u32x4 av = *(const u32x4*)&A[(size_t)(m0 + row) * K + k0 + kc * 8];
                *(u32x4*)&As[(kc * 128 + row) * 8] = av;
                u32x4 bv = *(const u32x4*)&Bt[(size_t)(n0 + row) * K + k0 + kc * 8];
                *(u32x4*)&Bs[(kc * 128 + row) * 8] = bv;
            }
        }
        __syncthreads();
        bf16x8 af[4], bf[4];
#pragma unroll
        for (int mi = 0; mi < 4; mi++)
            af[mi] = *(const bf16x8*)&As[(lg * 128 + wr * 64 + mi * 16 + lc) * 8];
#pragma unroll
        for (int ni = 0; ni < 4; ni++)
            bf[ni] = *(const bf16x8*)&Bs[(lg * 128 + wc * 64 + ni * 16 + lc) * 8];
#pragma unroll
        for (int mi = 0; mi < 4; mi++)
#pragma unroll
            for (int ni = 0; ni < 4; ni++)
                acc[mi][ni] = __builtin_amdgcn_mfma_f32_16x16x32_bf16(af[mi], bf[ni], acc[mi][ni], 0, 0, 0);
    }
#pragma unroll
    for (int mi = 0; mi < 4; mi++)
#pragma unroll
        for (int ni = 0; ni < 4; ni++)
#pragma unroll
            for (int r = 0; r < 4; r++) {
                int m = m0 + wr * 64 + mi * 16 + lg * 4 + r;
                int n = n0 + wc * 64 + ni * 16 + lc;
                float v = acc[mi][ni][r];
                if (MODE == 0) {
                    ((ushort*)C0)[(size_t)m * N + n] = f2b(v);
                } else if (MODE == 1) {
                    if (n < 1024) ((ushort*)C0)[(size_t)m * 1024 + n] = f2b(v);
                    else          ((ushort*)C1)[(size_t)m * 1024 + (n - 1024)] = f2b(v);
                } else {
                    ((float*)C0)[(size_t)m * N + n] = v + bias[n];
                }
            }
}

// ---------------- flash attention: per (b,h), QBLK=64, KVBLK=64 ----------------
__global__ __launch_bounds__(256) void attn(const ushort* __restrict__ qb, const ushort* __restrict__ kb,
                                            const ushort* __restrict__ vb, ushort* __restrict__ ob) {
    __shared__ ushort Qs[8 * 64 * 8];    // [dc][q][8]
    __shared__ ushort Ks[8 * 64 * 8];    // [dc][kv][8]
    __shared__ ushort Vt[8 * 64 * 8];    // [kvc][d][8]
    __shared__ ushort Ps[4][8 * 16 * 8]; // [wave][kvc][q][8]
    int qt = blockIdx.x, h = blockIdx.y, b = blockIdx.z;
    int t = threadIdx.x, l = t & 63, w = t >> 6;
    int lg = l >> 4, lc = l & 15;
    const ushort* Qg = qb + (size_t)b * NQ * INNER + (size_t)h * DH;
    const ushort* Kg = kb + (size_t)b * NKV * INNER + (size_t)h * DH;
    const ushort* Vg = vb + (size_t)b * NKV * INNER + (size_t)h * DH;
    int q0 = qt * 64;
    {
        int rr = t >> 3, dc = t & 7;
#pragma unroll
        for (int p = 0; p < 2; p++) {
            int row = p * 32 + rr;
            u32x4 v = *(const u32x4*)&Qg[(size_t)(q0 + row) * INNER + dc * 8];
            *(u32x4*)&Qs[(dc * 64 + row) * 8] = v;
        }
    }
    __syncthreads();
    bf16x8 qf[2];
#pragma unroll
    for (int kc = 0; kc < 2; kc++)
        qf[kc] = *(const bf16x8*)&Qs[((kc * 4 + lg) * 64 + w * 16 + lc) * 8];

    f32x4 o[4] = {};
    float m_[4] = {-1e30f, -1e30f, -1e30f, -1e30f};
    float s_[4] = {0.f, 0.f, 0.f, 0.f};

    for (int kv0 = 0; kv0 < NKV; kv0 += 64) {
        __syncthreads();
        {
            int rr = t >> 3, dc = t & 7;
#pragma unroll
            for (int p = 0; p < 2; p++) {
                int row = p * 32 + rr;
                u32x4 v = *(const u32x4*)&Kg[(size_t)(kv0 + row) * INNER + dc * 8];
                *(u32x4*)&Ks[(dc * 64 + row) * 8] = v;
            }
#pragma unroll
            for (int p = 0; p < 16; p++) {
                int idx = p * 256 + t;
                int kv = idx >> 6, d = idx & 63;
                ushort u = Vg[(size_t)(kv0 + kv) * INNER + d];
                Vt[((kv >> 3) * 64 + d) * 8 + (kv & 7)] = u;
            }
        }
        __syncthreads();
        // S = Q * K^T  (D-layout: row=q=lg*4+r, col=kv=nb*16+lc)
        f32x4 s[4] = {};
#pragma unroll
        for (int nb = 0; nb < 4; nb++)
#pragma unroll
            for (int kc = 0; kc < 2; kc++) {
                bf16x8 kf = *(const bf16x8*)&Ks[((kc * 4 + lg) * 64 + nb * 16 + lc) * 8];
                s[nb] = __builtin_amdgcn_mfma_f32_16x16x32_bf16(qf[kc], kf, s[nb], 0, 0, 0);
            }
#pragma unroll
        for (int nb = 0; nb < 4; nb++) s[nb] *= 0.125f;
        float p_[4][4];
#pragma unroll
        for (int r = 0; r < 4; r++) {
            float mx = fmaxf(fmaxf(s[0][r], s[1][r]), fmaxf(s[2][r], s[3][r]));
#pragma unroll
            for (int off = 8; off; off >>= 1) mx = fmaxf(mx, __shfl_xor(mx, off));
            float mn = fmaxf(m_[r], mx);
            float fac = __expf(m_[r] - mn);
            float rs = 0.f;
#pragma unroll
            for (int nb = 0; nb < 4; nb++) {
                float p = __expf(s[nb][r] - mn);
                p_[nb][r] = p;
                rs += p;
            }
#pragma unroll
            for (int off = 8; off; off >>= 1) rs += __shfl_xor(rs, off);
            s_[r] = s_[r] * fac + rs;
            m_[r] = mn;
#pragma unroll
            for (int nb = 0; nb < 4; nb++) o[nb][r] *= fac;
        }
        // write P (bf16) to per-wave LDS: [kvc][q][8]
#pragma unroll
        for (int nb = 0; nb < 4; nb++)
#pragma unroll
            for (int r = 0; r < 4; r++) {
                int q = lg * 4 + r;
                int addr = ((nb * 2 + (lc >> 3)) * 16 + q) * 8 + (lc & 7);
                Ps[w][addr] = f2b(p_[nb][r]);
            }
        // PV
        bf16x8 pf[2];
#pragma unroll
        for (int kc = 0; kc < 2; kc++)
            pf[kc] = *(const bf16x8*)&Ps[w][((kc * 4 + lg) * 16 + lc) * 8];
#pragma unroll
        for (int nb = 0; nb < 4; nb++)
#pragma unroll
            for (int kc = 0; kc < 2; kc++) {
                bf16x8 vf = *(const bf16x8*)&Vt[((kc * 4 + lg) * 64 + nb * 16 + lc) * 8];
                o[nb] = __builtin_amdgcn_mfma_f32_16x16x32_bf16(pf[kc], vf, o[nb], 0, 0, 0);
            }
    }
    ushort* Og = ob + (size_t)b * NQ * INNER + (size_t)h * DH;
#pragma unroll
    for (int nb = 0; nb < 4; nb++)
#pragma unroll
        for (int r = 0; r < 4; r++) {
            int q = q0 + w * 16 + lg * 4 + r;
            int d = nb * 16 + lc;
            Og[(size_t)q * INNER + d] = f2b(o[nb][r] / s_[r]);
        }
}

extern "C" void kernel_launch(void* const* d_in, const int* in_sizes, int n_in,
                              void* d_out, int out_size, void* d_ws, size_t ws_size,
                              hipStream_t stream) {
    const float* x    = (const float*)d_in[0];
    const float* ctx  = (const float*)d_in[1];
    const float* Wq   = (const float*)d_in[2];
    const float* Wkv  = (const float*)d_in[3];
    const float* Wout = (const float*)d_in[4];
    const float* bout = (const float*)d_in[5];
    float* out = (float*)d_out;

    if (ws_size < (size_t)(56u << 20)) return;  // need 56MB scratch
    char* ws = (char*)d_ws;
    ushort* xb    = (ushort*)(ws);
    ushort* cb    = (ushort*)(ws + (8u << 20));
    ushort* qb    = (ushort*)(ws + (16u << 20));
    ushort* kb    = (ushort*)(ws + (24u << 20));
    ushort* vb    = (ushort*)(ws + (32u << 20));
    ushort* ob    = (ushort*)(ws + (40u << 20));
    ushort* Wqt   = (ushort*)(ws + (48u << 20));
    ushort* Wkvt  = (ushort*)(ws + (50u << 20));
    ushort* Woutt = (ushort*)(ws + (54u << 20));

    cvt_f32_bf16<<<2048, 256, 0, stream>>>(x, xb, (BATCH * NQ * DIM) / 4);
    cvt_f32_bf16<<<2048, 256, 0, stream>>>(ctx, cb, (BATCH * NKV * DIM) / 4);
    transp_cvt<<<dim3(1024 / 32, 1024 / 32), dim3(32, 8), 0, stream>>>(Wq, Wqt, 1024, 1024);
    transp_cvt<<<dim3(2048 / 32, 1024 / 32), dim3(32, 8), 0, stream>>>(Wkv, Wkvt, 1024, 2048);
    transp_cvt<<<dim3(1024 / 32, 1024 / 32), dim3(32, 8), 0, stream>>>(Wout, Woutt, 1024, 1024);

    gemm_bt<0><<<dim3(1024 / 128, 4096 / 128), 256, 0, stream>>>(xb, Wqt, qb, nullptr, nullptr, 4096, 1024, 1024);
    gemm_bt<1><<<dim3(2048 / 128, 4096 / 128), 256, 0, stream>>>(cb, Wkvt, kb, vb, nullptr, 4096, 2048, 1024);
    attn<<<dim3(NQ / 64, HEADS, BATCH), 256, 0, stream>>>(qb, kb, vb, ob);
    gemm_bt<2><<<dim3(1024 / 128, 4096 / 128), 256, 0, stream>>>(ob, Woutt, out, nullptr, bout, 4096, 1024, 1024);
}

// Round 2
// 260.947 us; speedup vs baseline: 1.1821x; 1.1821x over previous
//
#include <hip/hip_runtime.h>
#include <hip/hip_bf16.h>
#include <stdint.h>

#define NQ 2048
#define NKV 2048
#define DIM 1024
#define INNER 1024
#define HEADS 16
#define DH 64
#define BATCH 2

typedef float f32x4 __attribute__((ext_vector_type(4)));
typedef __bf16 bf16x8 __attribute__((ext_vector_type(8)));
typedef unsigned int u32x4 __attribute__((ext_vector_type(4)));

__device__ inline ushort f2b(float f) {
    uint32_t u = __builtin_bit_cast(uint32_t, f);
    u += 0x7fff + ((u >> 16) & 1);   // round-to-nearest-even
    return (ushort)(u >> 16);
}

__device__ __forceinline__ void gload16(const void* g, void* lds) {
    __builtin_amdgcn_global_load_lds(
        (const __attribute__((address_space(1))) unsigned int*)g,
        (__attribute__((address_space(3))) unsigned int*)lds, 16, 0, 0);
}

// ---------------- fp32 -> bf16 convert (vectorized) ----------------
__global__ void cvt_f32_bf16(const float* __restrict__ in, ushort* __restrict__ out, int n4) {
    int i = blockIdx.x * blockDim.x + threadIdx.x;
    int stride = gridDim.x * blockDim.x;
    for (; i < n4; i += stride) {
        float4 v = ((const float4*)in)[i];
        ushort4 o;
        o.x = f2b(v.x); o.y = f2b(v.y); o.z = f2b(v.z); o.w = f2b(v.w);
        ((ushort4*)out)[i] = o;
    }
}

// ---------------- transpose + convert: in[R][C] f32 -> out[C][R] bf16 ----------------
__global__ void transp_cvt(const float* __restrict__ in, ushort* __restrict__ out, int R, int C) {
    __shared__ ushort tile[32][33];
    int c0 = blockIdx.x * 32, r0 = blockIdx.y * 32;
    int tx = threadIdx.x, ty = threadIdx.y;   // 32 x 8
#pragma unroll
    for (int i = 0; i < 4; i++)
        tile[ty + i * 8][tx] = f2b(in[(size_t)(r0 + ty + i * 8) * C + c0 + tx]);
    __syncthreads();
#pragma unroll
    for (int i = 0; i < 4; i++)
        out[(size_t)(c0 + ty + i * 8) * R + r0 + tx] = tile[tx][ty + i * 8];
}

// ---------------- bf16 transpose V: vb[b][kv][h*64+d] -> vtb[b][h][d][kv] ----------------
__global__ __launch_bounds__(256) void vtransp(const ushort* __restrict__ vb, ushort* __restrict__ vtb) {
    __shared__ ushort tile[64][72];
    int kt = blockIdx.x, h = blockIdx.y, b = blockIdx.z;
    int t = threadIdx.x;
    const ushort* src = vb + ((size_t)b * NKV + kt * 64) * INNER + h * DH;
#pragma unroll
    for (int p = 0; p < 2; p++) {
        int kv = p * 32 + (t >> 3), c0 = (t & 7) * 8;
        u32x4 v = *(const u32x4*)&src[(size_t)kv * INNER + c0];
        *(u32x4*)&tile[kv][c0] = v;
    }
    __syncthreads();
    ushort* dst = vtb + (((size_t)b * HEADS + h) * DH) * NKV + kt * 64;
#pragma unroll
    for (int p = 0; p < 2; p++) {
        int d = p * 32 + (t >> 3), k0 = (t & 7) * 8;
        ushort tmp[8];
#pragma unroll
        for (int j = 0; j < 8; j++) tmp[j] = tile[k0 + j][d];
        *(u32x4*)&dst[(size_t)d * NKV + k0] = *(u32x4*)tmp;
    }
}

// ---------------- bf16 GEMM: C[M][N] = A[M][K] * Bt[N][K]^T ----------------
// MODE 0: bf16 out (scaled) ; MODE 1: bf16 split k/v ; MODE 2: f32 out + bias
template <int MODE>
__global__ __launch_bounds__(256) void gemm_bt(const ushort* __restrict__ A, const ushort* __restrict__ Bt,
                                               void* __restrict__ C0, void* __restrict__ C1,
                                               const float* __restrict__ bias, float oscale,
                                               int M, int N, int K) {
    __shared__ ushort As[4 * 128 * 8];   // [kc][row][8]
    __shared__ ushort Bs[4 * 128 * 8];
    int m0 = blockIdx.y * 128, n0 = blockIdx.x * 128;
    int t = threadIdx.x, l = t & 63, w = t >> 6;
    int wr = w >> 1, wc = w & 1;
    int lg = l >> 4, lc = l & 15;
    f32x4 acc[4][4] = {};
    for (int k0 = 0; k0 < K; k0 += 32) {
        __syncthreads();
        {
            int s0 = w, s1 = w + 4;
            gload16(A + (size_t)(m0 + (s0 & 1) * 64 + l) * K + k0 + (s0 >> 1) * 8, &As[s0 * 512]);
            gload16(A + (size_t)(m0 + (s1 & 1) * 64 + l) * K + k0 + (s1 >> 1) * 8, &As[s1 * 512]);
            gload16(Bt + (size_t)(n0 + (s0 & 1) * 64 + l) * K + k0 + (s0 >> 1) * 8, &Bs[s0 * 512]);
            gload16(Bt + (size_t)(n0 + (s1 & 1) * 64 + l) * K + k0 + (s1 >> 1) * 8, &Bs[s1 * 512]);
        }
        __syncthreads();
        bf16x8 af[4], bf[4];
#pragma unroll
        for (int mi = 0; mi < 4; mi++)
            af[mi] = *(const bf16x8*)&As[(lg * 128 + wr * 64 + mi * 16 + lc) * 8];
#pragma unroll
        for (int ni = 0; ni < 4; ni++)
            bf[ni] = *(const bf16x8*)&Bs[(lg * 128 + wc * 64 + ni * 16 + lc) * 8];
#pragma unroll
        for (int mi = 0; mi < 4; mi++)
#pragma unroll
            for (int ni = 0; ni < 4; ni++)
                acc[mi][ni] = __builtin_amdgcn_mfma_f32_16x16x32_bf16(af[mi], bf[ni], acc[mi][ni], 0, 0, 0);
    }
#pragma unroll
    for (int mi = 0; mi < 4; mi++)
#pragma unroll
        for (int ni = 0; ni < 4; ni++)
#pragma unroll
            for (int r = 0; r < 4; r++) {
                int m = m0 + wr * 64 + mi * 16 + lg * 4 + r;
                int n = n0 + wc * 64 + ni * 16 + lc;
                float v = acc[mi][ni][r];
                if (MODE == 0) {
                    ((ushort*)C0)[(size_t)m * N + n] = f2b(v * oscale);
                } else if (MODE == 1) {
                    if (n < 1024) ((ushort*)C0)[(size_t)m * 1024 + n] = f2b(v);
                    else          ((ushort*)C1)[(size_t)m * 1024 + (n - 1024)] = f2b(v);
                } else {
                    ((float*)C0)[(size_t)m * N + n] = v + bias[n];
                }
            }
}

// ---------------- flash attention: QBLK=128 (4 waves x 32 rows), KVBLK=64 ----------------
// qb [b][q][h*64+d] (pre-scaled by 1/8), kb [b][kv][h*64+d], vtb [b][h][d][kv], ob [b][q][h*64+d]
__global__ __launch_bounds__(256) void attn2(const ushort* __restrict__ qb, const ushort* __restrict__ kb,
                                             const ushort* __restrict__ vtb, ushort* __restrict__ ob) {
    __shared__ ushort Qs[16 * 512];   // [dc 8][q 128][8]  16KB
    __shared__ ushort Ks[8 * 512];    // [dc 8][kv 64][8]   8KB
    __shared__ ushort Vs[8 * 512];    // [kvc 8][d 64][8]   8KB
    __shared__ ushort Ps[4 * 2048];   // per-wave [q 32][kv 64], XOR-swizzled  16KB
    int qt = blockIdx.x, h = blockIdx.y, b = blockIdx.z;
    int t = threadIdx.x, l = t & 63, w = t >> 6;
    int lg = l >> 4, lc = l & 15;
    const ushort* Qg = qb + ((size_t)b * NQ) * INNER + h * DH;
    const ushort* Kg = kb + ((size_t)b * NKV) * INNER + h * DH;
    const ushort* Vg = vtb + (((size_t)b * HEADS + h) * DH) * NKV;
    int q0 = qt * 128;
#pragma unroll
    for (int s2 = 0; s2 < 4; s2++) {
        int s = w * 4 + s2;
        gload16(Qg + (size_t)(q0 + (s & 1) * 64 + l) * INNER + (s >> 1) * 8, &Qs[s * 512]);
    }
    __syncthreads();
    bf16x8 qf[2][2];
#pragma unroll
    for (int mi = 0; mi < 2; mi++)
#pragma unroll
        for (int kc = 0; kc < 2; kc++)
            qf[mi][kc] = *(const bf16x8*)&Qs[((kc * 4 + lg) * 128 + w * 32 + mi * 16 + lc) * 8];

    f32x4 o[2][4] = {};
    float m_[2][4], s_[2][4];
#pragma unroll
    for (int mi = 0; mi < 2; mi++)
#pragma unroll
        for (int r = 0; r < 4; r++) { m_[mi][r] = -1e30f; s_[mi][r] = 0.f; }

    for (int kv0 = 0; kv0 < NKV; kv0 += 64) {
        __syncthreads();
        gload16(Kg + (size_t)(kv0 + l) * INNER + w * 8, &Ks[w * 512]);
        gload16(Kg + (size_t)(kv0 + l) * INNER + (w + 4) * 8, &Ks[(w + 4) * 512]);
        gload16(Vg + (size_t)l * NKV + kv0 + w * 8, &Vs[w * 512]);
        gload16(Vg + (size_t)l * NKV + kv0 + (w + 4) * 8, &Vs[(w + 4) * 512]);
        __syncthreads();
        f32x4 s[2][4] = {};
#pragma unroll
        for (int nb = 0; nb < 4; nb++)
#pragma unroll
            for (int kc = 0; kc < 2; kc++) {
                bf16x8 kf = *(const bf16x8*)&Ks[((kc * 4 + lg) * 64 + nb * 16 + lc) * 8];
#pragma unroll
                for (int mi = 0; mi < 2; mi++)
                    s[mi][nb] = __builtin_amdgcn_mfma_f32_16x16x32_bf16(qf[mi][kc], kf, s[mi][nb], 0, 0, 0);
            }
        // online softmax + P write (per-wave LDS, swizzled)
#pragma unroll
        for (int mi = 0; mi < 2; mi++) {
#pragma unroll
            for (int r = 0; r < 4; r++) {
                float mx = fmaxf(fmaxf(s[mi][0][r], s[mi][1][r]), fmaxf(s[mi][2][r], s[mi][3][r]));
#pragma unroll
                for (int off = 8; off; off >>= 1) mx = fmaxf(mx, __shfl_xor(mx, off));
                float mn = fmaxf(m_[mi][r], mx);
                float fac = __expf(m_[mi][r] - mn);
                m_[mi][r] = mn;
                int qq = mi * 16 + lg * 4 + r;
                int sw = (qq & 7) << 3;
                float rs = 0.f;
#pragma unroll
                for (int nb = 0; nb < 4; nb++) {
                    float p = __expf(s[mi][nb][r] - mn);
                    rs += p;
                    Ps[(w * 2048 + qq * 64 + nb * 16 + lc) ^ sw] = f2b(p);
                }
#pragma unroll
                for (int off = 8; off; off >>= 1) rs += __shfl_xor(rs, off);
                s_[mi][r] = s_[mi][r] * fac + rs;
#pragma unroll
                for (int nb = 0; nb < 4; nb++) o[mi][nb][r] = o[mi][nb][r] * fac;
            }
        }
        // PV
        bf16x8 vf[4][2];
#pragma unroll
        for (int nb = 0; nb < 4; nb++)
#pragma unroll
            for (int kc = 0; kc < 2; kc++)
                vf[nb][kc] = *(const bf16x8*)&Vs[((kc * 4 + lg) * 64 + nb * 16 + lc) * 8];
#pragma unroll
        for (int mi = 0; mi < 2; mi++) {
            bf16x8 pf[2];
#pragma unroll
            for (int kc = 0; kc < 2; kc++)
                pf[kc] = *(const bf16x8*)&Ps[(w * 2048 + (mi * 16 + lc) * 64 + kc * 32 + lg * 8) ^ ((lc & 7) << 3)];
#pragma unroll
            for (int nb = 0; nb < 4; nb++)
#pragma unroll
                for (int kc = 0; kc < 2; kc++)
                    o[mi][nb] = __builtin_amdgcn_mfma_f32_16x16x32_bf16(pf[kc], vf[nb][kc], o[mi][nb], 0, 0, 0);
        }
    }
    ushort* Og = ob + ((size_t)b * NQ) * INNER + h * DH;
#pragma unroll
    for (int mi = 0; mi < 2; mi++)
#pragma unroll
        for (int r = 0; r < 4; r++) {
            float inv = 1.f / s_[mi][r];
            int q = q0 + w * 32 + mi * 16 + lg * 4 + r;
#pragma unroll
            for (int nb = 0; nb < 4; nb++)
                Og[(size_t)q * INNER + nb * 16 + lc] = f2b(o[mi][nb][r] * inv);
        }
}

extern "C" void kernel_launch(void* const* d_in, const int* in_sizes, int n_in,
                              void* d_out, int out_size, void* d_ws, size_t ws_size,
                              hipStream_t stream) {
    const float* x    = (const float*)d_in[0];
    const float* ctx  = (const float*)d_in[1];
    const float* Wq   = (const float*)d_in[2];
    const float* Wkv  = (const float*)d_in[3];
    const float* Wout = (const float*)d_in[4];
    const float* bout = (const float*)d_in[5];
    float* out = (float*)d_out;

    if (ws_size < (size_t)(56u << 20)) return;  // need 56MB scratch
    char* ws = (char*)d_ws;
    ushort* xb    = (ushort*)(ws);                 // 8MB, dead after q-gemm
    ushort* vtb   = (ushort*)(ws);                 // reuse xb slot
    ushort* cb    = (ushort*)(ws + (8u << 20));    // 8MB, dead after kv-gemm
    ushort* ob    = (ushort*)(ws + (8u << 20));    // reuse cb slot
    ushort* qb    = (ushort*)(ws + (16u << 20));
    ushort* kb    = (ushort*)(ws + (24u << 20));
    ushort* vb    = (ushort*)(ws + (32u << 20));
    ushort* Wqt   = (ushort*)(ws + (48u << 20));
    ushort* Wkvt  = (ushort*)(ws + (50u << 20));
    ushort* Woutt = (ushort*)(ws + (54u << 20));

    cvt_f32_bf16<<<2048, 256, 0, stream>>>(x, xb, (BATCH * NQ * DIM) / 4);
    cvt_f32_bf16<<<2048, 256, 0, stream>>>(ctx, cb, (BATCH * NKV * DIM) / 4);
    transp_cvt<<<dim3(1024 / 32, 1024 / 32), dim3(32, 8), 0, stream>>>(Wq, Wqt, 1024, 1024);
    transp_cvt<<<dim3(2048 / 32, 1024 / 32), dim3(32, 8), 0, stream>>>(Wkv, Wkvt, 1024, 2048);
    transp_cvt<<<dim3(1024 / 32, 1024 / 32), dim3(32, 8), 0, stream>>>(Wout, Woutt, 1024, 1024);

    // q-proj (scaled by 1/8 for attention), kv-proj
    gemm_bt<0><<<dim3(8, 32), 256, 0, stream>>>(xb, Wqt, qb, nullptr, nullptr, 0.125f, 4096, 1024, 1024);
    gemm_bt<1><<<dim3(16, 32), 256, 0, stream>>>(cb, Wkvt, kb, vb, nullptr, 1.f, 4096, 2048, 1024);
    vtransp<<<dim3(32, 16, 2), 256, 0, stream>>>(vb, vtb);
    attn2<<<dim3(16, 16, 2), 256, 0, stream>>>(qb, kb, vtb, ob);
    gemm_bt<2><<<dim3(8, 32), 256, 0, stream>>>(ob, Woutt, out, nullptr, bout, 1.f, 4096, 1024, 1024);
}

// Round 5
// 202.001 us; speedup vs baseline: 1.5271x; 1.2918x over previous
//
#include <hip/hip_runtime.h>
#include <hip/hip_bf16.h>
#include <stdint.h>

#define NQ 2048
#define NKV 2048
#define DIM 1024
#define INNER 1024
#define HEADS 16
#define DH 64
#define BATCH 2

typedef float f32x4 __attribute__((ext_vector_type(4)));
typedef __bf16 bf16x8 __attribute__((ext_vector_type(8)));
typedef unsigned int u32x4 __attribute__((ext_vector_type(4)));

__device__ inline ushort f2b(float f) {
    uint32_t u = __builtin_bit_cast(uint32_t, f);
    u += 0x7fff + ((u >> 16) & 1);   // round-to-nearest-even
    return (ushort)(u >> 16);
}

__device__ inline uint pack2(float lo, float hi) {
    return (uint)f2b(lo) | ((uint)f2b(hi) << 16);
}

__device__ __forceinline__ void gload16(const void* g, void* lds) {
    __builtin_amdgcn_global_load_lds(
        (const __attribute__((address_space(1))) unsigned int*)g,
        (__attribute__((address_space(3))) unsigned int*)lds, 16, 0, 0);
}

// ---------------- fp32 -> bf16 convert (vectorized) ----------------
__global__ void cvt_f32_bf16(const float* __restrict__ in, ushort* __restrict__ out, int n4) {
    int i = blockIdx.x * blockDim.x + threadIdx.x;
    int stride = gridDim.x * blockDim.x;
    for (; i < n4; i += stride) {
        float4 v = ((const float4*)in)[i];
        ushort4 o;
        o.x = f2b(v.x); o.y = f2b(v.y); o.z = f2b(v.z); o.w = f2b(v.w);
        ((ushort4*)out)[i] = o;
    }
}

// ---------------- transpose + convert: in[R][C] f32 -> out[C][R] bf16 ----------------
__global__ void transp_cvt(const float* __restrict__ in, ushort* __restrict__ out, int R, int C) {
    __shared__ ushort tile[32][33];
    int c0 = blockIdx.x * 32, r0 = blockIdx.y * 32;
    int tx = threadIdx.x, ty = threadIdx.y;   // 32 x 8
#pragma unroll
    for (int i = 0; i < 4; i++)
        tile[ty + i * 8][tx] = f2b(in[(size_t)(r0 + ty + i * 8) * C + c0 + tx]);
    __syncthreads();
#pragma unroll
    for (int i = 0; i < 4; i++)
        out[(size_t)(c0 + ty + i * 8) * R + r0 + tx] = tile[tx][ty + i * 8];
}

// ---------------- bf16 transpose V: vb[b][kv][h*64+d] -> vtb[b][h][d][kv] ----------------
__global__ __launch_bounds__(256) void vtransp(const ushort* __restrict__ vb, ushort* __restrict__ vtb) {
    __shared__ ushort tile[64][72];
    int kt = blockIdx.x, h = blockIdx.y, b = blockIdx.z;
    int t = threadIdx.x;
    const ushort* src = vb + ((size_t)b * NKV + kt * 64) * INNER + h * DH;
#pragma unroll
    for (int p = 0; p < 2; p++) {
        int kv = p * 32 + (t >> 3), c0 = (t & 7) * 8;
        u32x4 v = *(const u32x4*)&src[(size_t)kv * INNER + c0];
        *(u32x4*)&tile[kv][c0] = v;
    }
    __syncthreads();
    ushort* dst = vtb + (((size_t)b * HEADS + h) * DH) * NKV + kt * 64;
#pragma unroll
    for (int p = 0; p < 2; p++) {
        int d = p * 32 + (t >> 3), k0 = (t & 7) * 8;
        ushort tmp[8];
#pragma unroll
        for (int j = 0; j < 8; j++) tmp[j] = tile[k0 + j][d];
        *(u32x4*)&dst[(size_t)d * NKV + k0] = *(u32x4*)tmp;
    }
}

// ---------------- bf16 GEMM: C[M][N] = A[M][K] * Bt[N][K]^T, 128 x BN tile ----------------
// MODE 0: bf16 out (scaled) ; MODE 1: bf16 split k/v ; MODE 2: f32 out + bias
template <int MODE, int BN>
__global__ __launch_bounds__(256) void gemm_bt(const ushort* __restrict__ A, const ushort* __restrict__ Bt,
                                               void* __restrict__ C0, void* __restrict__ C1,
                                               const float* __restrict__ bias, float oscale,
                                               int M, int N, int K) {
    constexpr int NI = BN / 32;           // n-blocks per wave
    __shared__ ushort As[2][4096];        // [kc4][row128][8]
    __shared__ ushort Bs[2][BN * 32];     // [kc4][rowBN][8]
    int m0 = blockIdx.y * 128, n0 = blockIdx.x * BN;
    int t = threadIdx.x, l = t & 63, w = t >> 6;
    int wr = w >> 1, wc = w & 1;
    int lg = l >> 4, lc = l & 15;
    f32x4 acc[4][NI] = {};

    auto stage = [&](int buf, int k0) {
#pragma unroll
        for (int i = 0; i < 2; i++) {
            int s = w + i * 4;
            gload16(A + (size_t)(m0 + (s & 1) * 64 + l) * K + k0 + (s >> 1) * 8, &As[buf][s * 512]);
        }
        if (BN == 128) {
#pragma unroll
            for (int i = 0; i < 2; i++) {
                int s = w + i * 4;
                gload16(Bt + (size_t)(n0 + (s & 1) * 64 + l) * K + k0 + (s >> 1) * 8, &Bs[buf][s * 512]);
            }
        } else {
            gload16(Bt + (size_t)(n0 + l) * K + k0 + w * 8, &Bs[buf][w * 512]);
        }
    };

    stage(0, 0);
    for (int k0 = 0, tt = 0; k0 < K; k0 += 32, ++tt) {
        __syncthreads();
        int cur = tt & 1;
        if (k0 + 32 < K) stage(cur ^ 1, k0 + 32);
        bf16x8 af[4], bf[NI];
#pragma unroll
        for (int mi = 0; mi < 4; mi++)
            af[mi] = *(const bf16x8*)&As[cur][(lg * 128 + wr * 64 + mi * 16 + lc) * 8];
#pragma unroll
        for (int ni = 0; ni < NI; ni++)
            bf[ni] = *(const bf16x8*)&Bs[cur][(lg * BN + wc * (BN / 2) + ni * 16 + lc) * 8];
        __builtin_amdgcn_s_setprio(1);
#pragma unroll
        for (int mi = 0; mi < 4; mi++)
#pragma unroll
            for (int ni = 0; ni < NI; ni++)
                acc[mi][ni] = __builtin_amdgcn_mfma_f32_16x16x32_bf16(af[mi], bf[ni], acc[mi][ni], 0, 0, 0);
        __builtin_amdgcn_s_setprio(0);
    }
#pragma unroll
    for (int mi = 0; mi < 4; mi++)
#pragma unroll
        for (int ni = 0; ni < NI; ni++)
#pragma unroll
            for (int r = 0; r < 4; r++) {
                int m = m0 + wr * 64 + mi * 16 + lg * 4 + r;
                int n = n0 + wc * (BN / 2) + ni * 16 + lc;
                float v = acc[mi][ni][r];
                if (MODE == 0) {
                    ((ushort*)C0)[(size_t)m * N + n] = f2b(v * oscale);
                } else if (MODE == 1) {
                    if (n < 1024) ((ushort*)C0)[(size_t)m * 1024 + n] = f2b(v);
                    else          ((ushort*)C1)[(size_t)m * 1024 + (n - 1024)] = f2b(v);
                } else {
                    ((float*)C0)[(size_t)m * N + n] = v + bias[n];
                }
            }
}

// ---------------- flash attention v3: swapped QK^T, in-register softmax ----------------
// QBLK=128 (4 waves x 32 q), KVBLK=64 dbuf. qb pre-scaled 1/8. vtb [b][h][d][kv].
__global__ __launch_bounds__(256, 2) void attn3(const ushort* __restrict__ qb, const ushort* __restrict__ kb,
                                                const ushort* __restrict__ vtb, ushort* __restrict__ ob) {
    __shared__ ushort Qs[8 * 128 * 8];   // [dc8][q128][8]    16KB
    __shared__ ushort Ks[2][4096];       // [dc8][kv64][8]    16KB
    __shared__ ushort Vs[2][4096];       // [kvc8][d64][8]    16KB
    __shared__ uint   Ps[4][1024];       // per-wave [q32][pair32] packed bf16x2, swizzled  16KB
    int flat = blockIdx.x;
    int swz = (flat & 7) * 64 + (flat >> 3);           // XCD-chunked (512 % 8 == 0)
    int qt = swz & 15, h = (swz >> 4) & 15, b = swz >> 8;
    int t = threadIdx.x, l = t & 63, w = t >> 6;
    int lg = l >> 4, lc = l & 15;
    int xsw = (lc << 1) & 0x1C;
    const ushort* Qg = qb + (size_t)b * NQ * INNER + h * DH;
    const ushort* Kg = kb + (size_t)b * NKV * INNER + h * DH;
    const ushort* Vg = vtb + (((size_t)b * HEADS + h) * DH) * NKV;
    int q0 = qt * 128;

    // stage Q (16 segments of 1KB)
#pragma unroll
    for (int i = 0; i < 4; i++) {
        int s = w * 4 + i;
        gload16(Qg + (size_t)(q0 + (s & 1) * 64 + l) * INNER + (s >> 1) * 8, &Qs[s * 512]);
    }
    auto stageKV = [&](int buf, int kv0) {
#pragma unroll
        for (int i = 0; i < 2; i++) {
            int s = w + i * 4;
            gload16(Kg + (size_t)(kv0 + l) * INNER + s * 8, &Ks[buf][s * 512]);
            gload16(Vg + (size_t)l * NKV + kv0 + s * 8, &Vs[buf][s * 512]);
        }
    };
    stageKV(0, 0);
    __syncthreads();

    bf16x8 qf[2][2];   // [mi][kc]: B-frag rows q = w*32 + mi*16 + lc
#pragma unroll
    for (int mi = 0; mi < 2; mi++)
#pragma unroll
        for (int kc = 0; kc < 2; kc++)
            qf[mi][kc] = *(const bf16x8*)&Qs[((kc * 4 + lg) * 128 + w * 32 + mi * 16 + lc) * 8];

    f32x4 o[2][4] = {};                 // O^T: [mi][nb d-block], row d = nb*16+lg*4+r, col q = lc
    float m_[2] = {-1e30f, -1e30f}, s_[2] = {0.f, 0.f};

    for (int tt = 0; tt < NKV / 64; ++tt) {
        int cur = tt & 1;
        if (tt + 1 < NKV / 64) stageKV(cur ^ 1, (tt + 1) * 64);
        // S^T[kv][q] = mfma(A=K rows, B=Q rows)
        f32x4 st[2][4] = {};
        __builtin_amdgcn_s_setprio(1);
#pragma unroll
        for (int kc = 0; kc < 2; kc++)
#pragma unroll
            for (int nb = 0; nb < 4; nb++) {
                bf16x8 kf = *(const bf16x8*)&Ks[cur][((kc * 4 + lg) * 64 + nb * 16 + lc) * 8];
                st[0][nb] = __builtin_amdgcn_mfma_f32_16x16x32_bf16(kf, qf[0][kc], st[0][nb], 0, 0, 0);
                st[1][nb] = __builtin_amdgcn_mfma_f32_16x16x32_bf16(kf, qf[1][kc], st[1][nb], 0, 0, 0);
            }
        __builtin_amdgcn_s_setprio(0);
        // per-mi in-register online softmax (lane owns q = mi*16+lc; kv = nb*16+lg*4+r)
#pragma unroll
        for (int mi = 0; mi < 2; mi++) {
            float mx = st[mi][0][0];
#pragma unroll
            for (int nb = 0; nb < 4; nb++)
#pragma unroll
                for (int r = 0; r < 4; r++) mx = fmaxf(mx, st[mi][nb][r]);
            mx = fmaxf(mx, __shfl_xor(mx, 16));
            mx = fmaxf(mx, __shfl_xor(mx, 32));
            float mn = fmaxf(m_[mi], mx);
            float fac = __expf(m_[mi] - mn);
            m_[mi] = mn;
            s_[mi] *= fac;
#pragma unroll
            for (int nb = 0; nb < 4; nb++) o[mi][nb] *= fac;
            float rs = 0.f;
#pragma unroll
            for (int nb = 0; nb < 4; nb++) {
                float p0 = __expf(st[mi][nb][0] - mn);
                float p1 = __expf(st[mi][nb][1] - mn);
                float p2 = __expf(st[mi][nb][2] - mn);
                float p3 = __expf(st[mi][nb][3] - mn);
                rs += (p0 + p1) + (p2 + p3);
                uint2 pw;
                pw.x = pack2(p0, p1);
                pw.y = pack2(p2, p3);
                *(uint2*)&Ps[w][(mi * 16 + lc) * 32 + ((nb * 8 + lg * 2) ^ xsw)] = pw;
            }
            rs += __shfl_xor(rs, 16);
            rs += __shfl_xor(rs, 32);
            s_[mi] += rs;
        }
        // compiler-level memory fence: forbid hoisting the P reads above the P writes
        asm volatile("" ::: "memory");
        // PV: O^T[d][q] += mfma(A=V^T rows d, B=P rows q)
        bf16x8 pf[2][2], vf[4][2];
#pragma unroll
        for (int mi = 0; mi < 2; mi++)
#pragma unroll
            for (int kc = 0; kc < 2; kc++)
                pf[mi][kc] = *(const bf16x8*)&Ps[w][(mi * 16 + lc) * 32 + ((kc * 16 + lg * 4) ^ xsw)];
#pragma unroll
        for (int nb = 0; nb < 4; nb++)
#pragma unroll
            for (int kc = 0; kc < 2; kc++)
                vf[nb][kc] = *(const bf16x8*)&Vs[cur][((kc * 4 + lg) * 64 + nb * 16 + lc) * 8];
        __builtin_amdgcn_s_setprio(1);
#pragma unroll
        for (int nb = 0; nb < 4; nb++)
#pragma unroll
            for (int kc = 0; kc < 2; kc++) {
                o[0][nb] = __builtin_amdgcn_mfma_f32_16x16x32_bf16(vf[nb][kc], pf[0][kc], o[0][nb], 0, 0, 0);
                o[1][nb] = __builtin_amdgcn_mfma_f32_16x16x32_bf16(vf[nb][kc], pf[1][kc], o[1][nb], 0, 0, 0);
            }
        __builtin_amdgcn_s_setprio(0);
        __syncthreads();
    }
    ushort* Og = ob + (size_t)b * NQ * INNER + h * DH;
#pragma unroll
    for (int mi = 0; mi < 2; mi++) {
        float inv = 1.f / s_[mi];
        int q = q0 + w * 32 + mi * 16 + lc;
#pragma unroll
        for (int nb = 0; nb < 4; nb++) {
            uint2 pw;
            pw.x = pack2(o[mi][nb][0] * inv, o[mi][nb][1] * inv);
            pw.y = pack2(o[mi][nb][2] * inv, o[mi][nb][3] * inv);
            *(uint2*)&Og[(size_t)q * INNER + nb * 16 + lg * 4] = pw;
        }
    }
}

extern "C" void kernel_launch(void* const* d_in, const int* in_sizes, int n_in,
                              void* d_out, int out_size, void* d_ws, size_t ws_size,
                              hipStream_t stream) {
    const float* x    = (const float*)d_in[0];
    const float* ctx  = (const float*)d_in[1];
    const float* Wq   = (const float*)d_in[2];
    const float* Wkv  = (const float*)d_in[3];
    const float* Wout = (const float*)d_in[4];
    const float* bout = (const float*)d_in[5];
    float* out = (float*)d_out;

    if (ws_size < (size_t)(56u << 20)) return;  // need 56MB scratch
    char* ws = (char*)d_ws;
    ushort* xb    = (ushort*)(ws);                 // 8MB, dead after q-gemm
    ushort* vtb   = (ushort*)(ws);                 // reuse xb slot
    ushort* cb    = (ushort*)(ws + (8u << 20));    // 8MB, dead after kv-gemm
    ushort* ob    = (ushort*)(ws + (8u << 20));    // reuse cb slot
    ushort* qb    = (ushort*)(ws + (16u << 20));
    ushort* kb    = (ushort*)(ws + (24u << 20));
    ushort* vb    = (ushort*)(ws + (32u << 20));
    ushort* Wqt   = (ushort*)(ws + (48u << 20));
    ushort* Wkvt  = (ushort*)(ws + (50u << 20));
    ushort* Woutt = (ushort*)(ws + (54u << 20));

    cvt_f32_bf16<<<2048, 256, 0, stream>>>(x, xb, (BATCH * NQ * DIM) / 4);
    cvt_f32_bf16<<<2048, 256, 0, stream>>>(ctx, cb, (BATCH * NKV * DIM) / 4);
    transp_cvt<<<dim3(1024 / 32, 1024 / 32), dim3(32, 8), 0, stream>>>(Wq, Wqt, 1024, 1024);
    transp_cvt<<<dim3(2048 / 32, 1024 / 32), dim3(32, 8), 0, stream>>>(Wkv, Wkvt, 1024, 2048);
    transp_cvt<<<dim3(1024 / 32, 1024 / 32), dim3(32, 8), 0, stream>>>(Wout, Woutt, 1024, 1024);

    // q-proj (scaled by 1/8 for attention), kv-proj
    gemm_bt<0, 64><<<dim3(16, 32), 256, 0, stream>>>(xb, Wqt, qb, nullptr, nullptr, 0.125f, 4096, 1024, 1024);
    gemm_bt<1, 128><<<dim3(16, 32), 256, 0, stream>>>(cb, Wkvt, kb, vb, nullptr, 1.f, 4096, 2048, 1024);
    vtransp<<<dim3(32, 16, 2), 256, 0, stream>>>(vb, vtb);
    attn3<<<512, 256, 0, stream>>>(qb, kb, vtb, ob);
    gemm_bt<2, 64><<<dim3(16, 32), 256, 0, stream>>>(ob, Woutt, out, nullptr, bout, 1.f, 4096, 1024, 1024);
}

// Round 7
// 190.842 us; speedup vs baseline: 1.6164x; 1.0585x over previous
//
#include <hip/hip_runtime.h>
#include <hip/hip_bf16.h>
#include <stdint.h>

#define NQ 2048
#define NKV 2048
#define DIM 1024
#define INNER 1024
#define HEADS 16
#define DH 64
#define BATCH 2

typedef float f32x4 __attribute__((ext_vector_type(4)));
typedef __bf16 bf16x8 __attribute__((ext_vector_type(8)));
typedef unsigned int u32x4 __attribute__((ext_vector_type(4)));

__device__ inline ushort f2b(float f) {
    uint32_t u = __builtin_bit_cast(uint32_t, f);
    u += 0x7fff + ((u >> 16) & 1);   // round-to-nearest-even
    return (ushort)(u >> 16);
}

__device__ inline uint pkbf16(float lo, float hi) {
    __hip_bfloat162 h = __float22bfloat162_rn(make_float2(lo, hi));
    uint r;
    __builtin_memcpy(&r, &h, 4);   // low 16 = bf16(lo), high 16 = bf16(hi)
    return r;
}

__device__ __forceinline__ void gload16(const void* g, void* lds) {
    __builtin_amdgcn_global_load_lds(
        (const __attribute__((address_space(1))) unsigned int*)g,
        (__attribute__((address_space(3))) unsigned int*)lds, 16, 0, 0);
}

// ---------------- fp32 -> bf16 convert (vectorized) ----------------
__global__ void cvt_f32_bf16(const float* __restrict__ in, ushort* __restrict__ out, int n4) {
    int i = blockIdx.x * blockDim.x + threadIdx.x;
    int stride = gridDim.x * blockDim.x;
    for (; i < n4; i += stride) {
        float4 v = ((const float4*)in)[i];
        ushort4 o;
        o.x = f2b(v.x); o.y = f2b(v.y); o.z = f2b(v.z); o.w = f2b(v.w);
        ((ushort4*)out)[i] = o;
    }
}

// ---------------- transpose + convert: in[R][C] f32 -> out[C][R] bf16 ----------------
__global__ void transp_cvt(const float* __restrict__ in, ushort* __restrict__ out, int R, int C) {
    __shared__ ushort tile[32][33];
    int c0 = blockIdx.x * 32, r0 = blockIdx.y * 32;
    int tx = threadIdx.x, ty = threadIdx.y;   // 32 x 8
#pragma unroll
    for (int i = 0; i < 4; i++)
        tile[ty + i * 8][tx] = f2b(in[(size_t)(r0 + ty + i * 8) * C + c0 + tx]);
    __syncthreads();
#pragma unroll
    for (int i = 0; i < 4; i++)
        out[(size_t)(c0 + ty + i * 8) * R + r0 + tx] = tile[tx][ty + i * 8];
}

// ---------------- bf16 transpose V: vb[b][kv][h*64+d] -> vtb[b][h][d][kv] ----------------
__global__ __launch_bounds__(256) void vtransp(const ushort* __restrict__ vb, ushort* __restrict__ vtb) {
    __shared__ ushort tile[64][72];
    int kt = blockIdx.x, h = blockIdx.y, b = blockIdx.z;
    int t = threadIdx.x;
    const ushort* src = vb + ((size_t)b * NKV + kt * 64) * INNER + h * DH;
#pragma unroll
    for (int p = 0; p < 2; p++) {
        int kv = p * 32 + (t >> 3), c0 = (t & 7) * 8;
        u32x4 v = *(const u32x4*)&src[(size_t)kv * INNER + c0];
        *(u32x4*)&tile[kv][c0] = v;
    }
    __syncthreads();
    ushort* dst = vtb + (((size_t)b * HEADS + h) * DH) * NKV + kt * 64;
#pragma unroll
    for (int p = 0; p < 2; p++) {
        int d = p * 32 + (t >> 3), k0 = (t & 7) * 8;
        ushort tmp[8];
#pragma unroll
        for (int j = 0; j < 8; j++) tmp[j] = tile[k0 + j][d];
        *(u32x4*)&dst[(size_t)d * NKV + k0] = *(u32x4*)tmp;
    }
}

// ---------------- bf16 GEMM: C[M][N] = A[M][K] * Bt[N][K]^T, 128 x BN tile ----------------
// MODE 0: bf16 out (scaled) ; MODE 1: bf16 split k/v ; MODE 2: f32 out + bias
template <int MODE, int BN>
__global__ __launch_bounds__(256) void gemm_bt(const ushort* __restrict__ A, const ushort* __restrict__ Bt,
                                               void* __restrict__ C0, void* __restrict__ C1,
                                               const float* __restrict__ bias, float oscale,
                                               int M, int N, int K) {
    constexpr int NI = BN / 32;           // n-blocks per wave
    __shared__ ushort As[2][4096];        // [kc4][row128][8]
    __shared__ ushort Bs[2][BN * 32];     // [kc4][rowBN][8]
    int m0 = blockIdx.y * 128, n0 = blockIdx.x * BN;
    int t = threadIdx.x, l = t & 63, w = t >> 6;
    int wr = w >> 1, wc = w & 1;
    int lg = l >> 4, lc = l & 15;
    f32x4 acc[4][NI] = {};

    auto stage = [&](int buf, int k0) {
#pragma unroll
        for (int i = 0; i < 2; i++) {
            int s = w + i * 4;
            gload16(A + (size_t)(m0 + (s & 1) * 64 + l) * K + k0 + (s >> 1) * 8, &As[buf][s * 512]);
        }
        if (BN == 128) {
#pragma unroll
            for (int i = 0; i < 2; i++) {
                int s = w + i * 4;
                gload16(Bt + (size_t)(n0 + (s & 1) * 64 + l) * K + k0 + (s >> 1) * 8, &Bs[buf][s * 512]);
            }
        } else {
            gload16(Bt + (size_t)(n0 + l) * K + k0 + w * 8, &Bs[buf][w * 512]);
        }
    };

    stage(0, 0);
    for (int k0 = 0, tt = 0; k0 < K; k0 += 32, ++tt) {
        __syncthreads();
        int cur = tt & 1;
        if (k0 + 32 < K) stage(cur ^ 1, k0 + 32);
        bf16x8 af[4], bf[NI];
#pragma unroll
        for (int mi = 0; mi < 4; mi++)
            af[mi] = *(const bf16x8*)&As[cur][(lg * 128 + wr * 64 + mi * 16 + lc) * 8];
#pragma unroll
        for (int ni = 0; ni < NI; ni++)
            bf[ni] = *(const bf16x8*)&Bs[cur][(lg * BN + wc * (BN / 2) + ni * 16 + lc) * 8];
        __builtin_amdgcn_s_setprio(1);
#pragma unroll
        for (int mi = 0; mi < 4; mi++)
#pragma unroll
            for (int ni = 0; ni < NI; ni++)
                acc[mi][ni] = __builtin_amdgcn_mfma_f32_16x16x32_bf16(af[mi], bf[ni], acc[mi][ni], 0, 0, 0);
        __builtin_amdgcn_s_setprio(0);
    }
#pragma unroll
    for (int mi = 0; mi < 4; mi++)
#pragma unroll
        for (int ni = 0; ni < NI; ni++)
#pragma unroll
            for (int r = 0; r < 4; r++) {
                int m = m0 + wr * 64 + mi * 16 + lg * 4 + r;
                int n = n0 + wc * (BN / 2) + ni * 16 + lc;
                float v = acc[mi][ni][r];
                if (MODE == 0) {
                    ((ushort*)C0)[(size_t)m * N + n] = f2b(v * oscale);
                } else if (MODE == 1) {
                    if (n < 1024) ((ushort*)C0)[(size_t)m * 1024 + n] = f2b(v);
                    else          ((ushort*)C1)[(size_t)m * 1024 + (n - 1024)] = f2b(v);
                } else {
                    ((float*)C0)[(size_t)m * N + n] = v + bias[n];
                }
            }
}

// ---------------- flash attention v4: swapped QK^T, in-reg softmax (exp2), P aliases Q-LDS ----------------
// QBLK=128 (4 waves x 32 q), KVBLK=64 dbuf. qb pre-scaled by 0.125*log2e. vtb [b][h][d][kv].
__global__ __launch_bounds__(256, 3) void attn3(const ushort* __restrict__ qb, const ushort* __restrict__ kb,
                                                const ushort* __restrict__ vtb, ushort* __restrict__ ob) {
    __shared__ ushort Qs[8 * 128 * 8];   // [dc8][q128][8] 16KB; reused as P after Q consumed
    __shared__ ushort Ks[2][4096];       // [dc8][kv64][8]    16KB
    __shared__ ushort Vs[2][4096];       // [kvc8][d64][8]    16KB
    uint* Psw = (uint*)Qs;               // per-wave 1024 uints: [q32][pair32], swizzled
    int flat = blockIdx.x;
    int swz = (flat & 7) * 64 + (flat >> 3);           // XCD-chunked (512 % 8 == 0)
    int qt = swz & 15, h = (swz >> 4) & 15, b = swz >> 8;
    int t = threadIdx.x, l = t & 63, w = t >> 6;
    int lg = l >> 4, lc = l & 15;
    int xsw = (lc << 1) & 0x1C;
    const ushort* Qg = qb + (size_t)b * NQ * INNER + h * DH;
    const ushort* Kg = kb + (size_t)b * NKV * INNER + h * DH;
    const ushort* Vg = vtb + (((size_t)b * HEADS + h) * DH) * NKV;
    int q0 = qt * 128;

    // stage Q (16 segments of 1KB)
#pragma unroll
    for (int i = 0; i < 4; i++) {
        int s = w * 4 + i;
        gload16(Qg + (size_t)(q0 + (s & 1) * 64 + l) * INNER + (s >> 1) * 8, &Qs[s * 512]);
    }
    auto stageKV = [&](int buf, int kv0) {
#pragma unroll
        for (int i = 0; i < 2; i++) {
            int s = w + i * 4;
            gload16(Kg + (size_t)(kv0 + l) * INNER + s * 8, &Ks[buf][s * 512]);
            gload16(Vg + (size_t)l * NKV + kv0 + s * 8, &Vs[buf][s * 512]);
        }
    };
    stageKV(0, 0);
    __syncthreads();

    bf16x8 qf[2][2];   // [mi][kc]: B-frag rows q = w*32 + mi*16 + lc
#pragma unroll
    for (int mi = 0; mi < 2; mi++)
#pragma unroll
        for (int kc = 0; kc < 2; kc++)
            qf[mi][kc] = *(const bf16x8*)&Qs[((kc * 4 + lg) * 128 + w * 32 + mi * 16 + lc) * 8];
    __syncthreads();   // all waves done reading Q before Qs is reused as P

    uint* Ps = Psw + w * 1024;
    f32x4 o[2][4] = {};                 // O^T: [mi][nb d-block], row d = nb*16+lg*4+r, col q = lc
    float m_[2] = {-1e30f, -1e30f}, s_[2] = {0.f, 0.f};

    for (int tt = 0; tt < NKV / 64; ++tt) {
        int cur = tt & 1;
        if (tt + 1 < NKV / 64) stageKV(cur ^ 1, (tt + 1) * 64);
        // S^T[kv][q] = mfma(A=K rows, B=Q rows), in log2 units
        f32x4 st[2][4] = {};
        __builtin_amdgcn_s_setprio(1);
#pragma unroll
        for (int kc = 0; kc < 2; kc++)
#pragma unroll
            for (int nb = 0; nb < 4; nb++) {
                bf16x8 kf = *(const bf16x8*)&Ks[cur][((kc * 4 + lg) * 64 + nb * 16 + lc) * 8];
                st[0][nb] = __builtin_amdgcn_mfma_f32_16x16x32_bf16(kf, qf[0][kc], st[0][nb], 0, 0, 0);
                st[1][nb] = __builtin_amdgcn_mfma_f32_16x16x32_bf16(kf, qf[1][kc], st[1][nb], 0, 0, 0);
            }
        __builtin_amdgcn_s_setprio(0);
        // per-mi in-register online softmax (lane owns q = mi*16+lc; kv = nb*16+lg*4+r)
#pragma unroll
        for (int mi = 0; mi < 2; mi++) {
            float mx = st[mi][0][0];
#pragma unroll
            for (int nb = 0; nb < 4; nb++)
#pragma unroll
                for (int r = 0; r < 4; r++) mx = fmaxf(mx, st[mi][nb][r]);
            mx = fmaxf(mx, __shfl_xor(mx, 16));
            mx = fmaxf(mx, __shfl_xor(mx, 32));
            float mn = fmaxf(m_[mi], mx);
            float fac = __builtin_amdgcn_exp2f(m_[mi] - mn);
            m_[mi] = mn;
            s_[mi] *= fac;
#pragma unroll
            for (int nb = 0; nb < 4; nb++) o[mi][nb] *= fac;
            float rs = 0.f;
#pragma unroll
            for (int nb = 0; nb < 4; nb++) {
                float p0 = __builtin_amdgcn_exp2f(st[mi][nb][0] - mn);
                float p1 = __builtin_amdgcn_exp2f(st[mi][nb][1] - mn);
                float p2 = __builtin_amdgcn_exp2f(st[mi][nb][2] - mn);
                float p3 = __builtin_amdgcn_exp2f(st[mi][nb][3] - mn);
                rs += (p0 + p1) + (p2 + p3);
                uint2 pw;
                pw.x = pkbf16(p0, p1);
                pw.y = pkbf16(p2, p3);
                *(uint2*)&Ps[(mi * 16 + lc) * 32 + ((nb * 8 + lg * 2) ^ xsw)] = pw;
            }
            rs += __shfl_xor(rs, 16);
            rs += __shfl_xor(rs, 32);
            s_[mi] += rs;
        }
        // compiler-level memory fence: forbid hoisting the P reads above the P writes
        asm volatile("" ::: "memory");
        // PV: O^T[d][q] += mfma(A=V^T rows d, B=P rows q)
        bf16x8 pf[2][2], vf[4][2];
#pragma unroll
        for (int mi = 0; mi < 2; mi++)
#pragma unroll
            for (int kc = 0; kc < 2; kc++)
                pf[mi][kc] = *(const bf16x8*)&Ps[(mi * 16 + lc) * 32 + ((kc * 16 + lg * 4) ^ xsw)];
#pragma unroll
        for (int nb = 0; nb < 4; nb++)
#pragma unroll
            for (int kc = 0; kc < 2; kc++)
                vf[nb][kc] = *(const bf16x8*)&Vs[cur][((kc * 4 + lg) * 64 + nb * 16 + lc) * 8];
        __builtin_amdgcn_s_setprio(1);
#pragma unroll
        for (int nb = 0; nb < 4; nb++)
#pragma unroll
            for (int kc = 0; kc < 2; kc++) {
                o[0][nb] = __builtin_amdgcn_mfma_f32_16x16x32_bf16(vf[nb][kc], pf[0][kc], o[0][nb], 0, 0, 0);
                o[1][nb] = __builtin_amdgcn_mfma_f32_16x16x32_bf16(vf[nb][kc], pf[1][kc], o[1][nb], 0, 0, 0);
            }
        __builtin_amdgcn_s_setprio(0);
        __syncthreads();
    }
    ushort* Og = ob + (size_t)b * NQ * INNER + h * DH;
#pragma unroll
    for (int mi = 0; mi < 2; mi++) {
        float inv = 1.f / s_[mi];
        int q = q0 + w * 32 + mi * 16 + lc;
#pragma unroll
        for (int nb = 0; nb < 4; nb++) {
            uint2 pw;
            pw.x = pkbf16(o[mi][nb][0] * inv, o[mi][nb][1] * inv);
            pw.y = pkbf16(o[mi][nb][2] * inv, o[mi][nb][3] * inv);
            *(uint2*)&Og[(size_t)q * INNER + nb * 16 + lg * 4] = pw;
        }
    }
}

extern "C" void kernel_launch(void* const* d_in, const int* in_sizes, int n_in,
                              void* d_out, int out_size, void* d_ws, size_t ws_size,
                              hipStream_t stream) {
    const float* x    = (const float*)d_in[0];
    const float* ctx  = (const float*)d_in[1];
    const float* Wq   = (const float*)d_in[2];
    const float* Wkv  = (const float*)d_in[3];
    const float* Wout = (const float*)d_in[4];
    const float* bout = (const float*)d_in[5];
    float* out = (float*)d_out;

    if (ws_size < (size_t)(56u << 20)) return;  // need 56MB scratch
    char* ws = (char*)d_ws;
    ushort* xb    = (ushort*)(ws);                 // 8MB, dead after q-gemm
    ushort* vtb   = (ushort*)(ws);                 // reuse xb slot
    ushort* cb    = (ushort*)(ws + (8u << 20));    // 8MB, dead after kv-gemm
    ushort* ob    = (ushort*)(ws + (8u << 20));    // reuse cb slot
    ushort* qb    = (ushort*)(ws + (16u << 20));
    ushort* kb    = (ushort*)(ws + (24u << 20));
    ushort* vb    = (ushort*)(ws + (32u << 20));
    ushort* Wqt   = (ushort*)(ws + (48u << 20));
    ushort* Wkvt  = (ushort*)(ws + (50u << 20));
    ushort* Woutt = (ushort*)(ws + (54u << 20));

    cvt_f32_bf16<<<2048, 256, 0, stream>>>(x, xb, (BATCH * NQ * DIM) / 4);
    cvt_f32_bf16<<<2048, 256, 0, stream>>>(ctx, cb, (BATCH * NKV * DIM) / 4);
    transp_cvt<<<dim3(1024 / 32, 1024 / 32), dim3(32, 8), 0, stream>>>(Wq, Wqt, 1024, 1024);
    transp_cvt<<<dim3(2048 / 32, 1024 / 32), dim3(32, 8), 0, stream>>>(Wkv, Wkvt, 1024, 2048);
    transp_cvt<<<dim3(1024 / 32, 1024 / 32), dim3(32, 8), 0, stream>>>(Wout, Woutt, 1024, 1024);

    // q-proj scaled by 0.125 * log2(e) so attention logits are in exp2 units
    gemm_bt<0, 64><<<dim3(16, 32), 256, 0, stream>>>(xb, Wqt, qb, nullptr, nullptr, 0.125f * 1.44269504f, 4096, 1024, 1024);
    gemm_bt<1, 128><<<dim3(16, 32), 256, 0, stream>>>(cb, Wkvt, kb, vb, nullptr, 1.f, 4096, 2048, 1024);
    vtransp<<<dim3(32, 16, 2), 256, 0, stream>>>(vb, vtb);
    attn3<<<512, 256, 0, stream>>>(qb, kb, vtb, ob);
    gemm_bt<2, 64><<<dim3(16, 32), 256, 0, stream>>>(ob, Woutt, out, nullptr, bout, 1.f, 4096, 1024, 1024);
}